// Round 8
// baseline (328.387 us; speedup 1.0000x reference)
//
#include <hip/hip_runtime.h>

typedef __bf16 bf16;
typedef __bf16 bf16x8 __attribute__((ext_vector_type(8)));
typedef __bf16 bf16x4 __attribute__((ext_vector_type(4)));
typedef float  f32x4  __attribute__((ext_vector_type(4)));

#define GLD_LDS16(gp, lp) __builtin_amdgcn_global_load_lds( \
    (const __attribute__((address_space(1))) unsigned int*)(const void*)(gp), \
    (__attribute__((address_space(3))) unsigned int*)(void*)(lp), 16, 0, 0)

constexpr int BB = 4, SSEQ = 2048, DK = 1024, NH = 16, DH = 64;
constexpr int M = BB * SSEQ;                    // 8192 rows

constexpr size_t SZ_X = (size_t)M * DK * 2;     // 16 MiB
constexpr size_t SZ_W = (size_t)DK * DK * 2;    // 2 MiB
constexpr size_t OFF_QBF = 0;
constexpr size_t OFF_KBF = OFF_QBF + SZ_X;
constexpr size_t OFF_VBF = OFF_KBF + SZ_X;
constexpr size_t OFF_WQT = OFF_VBF + SZ_X;
constexpr size_t OFF_WKT = OFF_WQT + SZ_W;
constexpr size_t OFF_WVT = OFF_WKT + SZ_W;
constexpr size_t OFF_WUT = OFF_WVT + SZ_W;
constexpr size_t OFF_QH  = OFF_WUT + SZ_W;      // (B,S,1024) bf16 flat
constexpr size_t OFF_KH  = OFF_QH + SZ_X;       // (B,S,1024) bf16 flat
constexpr size_t OFF_VTH = OFF_KH + SZ_X;       // (B,H,64,S) bf16 (transposed)
constexpr size_t OFF_MRG = OFF_VTH + SZ_X;      // (B,S,1024) bf16

// ---------------------------------------------------------------- converts
__global__ void cvt_x(const float* __restrict__ q, const float* __restrict__ k,
                      const float* __restrict__ v,
                      bf16* __restrict__ qb, bf16* __restrict__ kb, bf16* __restrict__ vb) {
    const float* s = (blockIdx.z == 0) ? q : (blockIdx.z == 1) ? k : v;
    bf16*        d = (blockIdx.z == 0) ? qb : (blockIdx.z == 1) ? kb : vb;
    size_t i = (size_t)blockIdx.x * blockDim.x + threadIdx.x;
    float4 val = ((const float4*)s)[i];
    bf16x4 o = { (bf16)val.x, (bf16)val.y, (bf16)val.z, (bf16)val.w };
    ((bf16x4*)d)[i] = o;
}

__global__ void cvt_wT(const float* __restrict__ wq, const float* __restrict__ wk,
                       const float* __restrict__ wv, const float* __restrict__ wu,
                       bf16* __restrict__ wqt, bf16* __restrict__ wkt,
                       bf16* __restrict__ wvt, bf16* __restrict__ wut) {
    const float* w = (blockIdx.z == 0) ? wq : (blockIdx.z == 1) ? wk
                   : (blockIdx.z == 2) ? wv : wu;
    bf16* o        = (blockIdx.z == 0) ? wqt : (blockIdx.z == 1) ? wkt
                   : (blockIdx.z == 2) ? wvt : wut;
    __shared__ float t[64][65];
    int tx = threadIdx.x & 63, ty = threadIdx.x >> 6;
    int bx = blockIdx.x * 64, by = blockIdx.y * 64;
#pragma unroll
    for (int r = 0; r < 16; r++) {
        int row = ty * 16 + r;
        t[row][tx] = w[(size_t)(by + row) * DK + bx + tx];
    }
    __syncthreads();
#pragma unroll
    for (int r = 0; r < 16; r++) {
        int row2 = ty * 16 + r;
        o[(size_t)(bx + row2) * DK + by + tx] = (bf16)t[tx][row2];
    }
}

// ---------------------------------------------------------------- GEMM (C = A @ BT^T + bias)
// R7 (verified: QKV ~66us, race-free): 8-wave 128x256x64 tile, T3+T4 schedule
// (raw s_barrier + counted vmcnt(6)), T2 XOR-swizzle via pre-swizzled global
// source (rule #21), T5 setprio. Sync proof: BAR1 after vmcnt(6): tile t landed.
// BAR2 after lgkmcnt(0): all reads of buf[cur] retired -> stage(t+2) may
// overwrite. 6 loads/thread/tile; 2 tiles in flight -> vmcnt(6).
// Grid 256/z: QKV 768 = 3 rounds of 256 CUs, proj 256 = 1.
// mode 0: out bf16 row-major; mode 1: out bf16 (B,H,64,S); mode 2: out f32
struct GArg {
    const bf16* A; const bf16* BT; const float* bias; void* out; int mode; float oscale;
};

__global__ __launch_bounds__(512, 2) void gemm_bt(GArg g0, GArg g1, GArg g2) {
    GArg g;
    if (blockIdx.z == 0) g = g0; else if (blockIdx.z == 1) g = g1; else g = g2;
    __shared__ __attribute__((aligned(16))) bf16 As[2][128 * 64];   // 32 KB
    __shared__ __attribute__((aligned(16))) bf16 Bs[2][256 * 64];   // 64 KB
    const int tid = threadIdx.x;                 // 0..511
    const int lane = tid & 63, wv = tid >> 6;    // 8 waves
    const int wm = (wv >> 2) * 64;               // 0,64   (2 row-groups)
    const int wn = (wv & 3) * 64;                // 0..192 (4 col-groups)
    const int cl = lane & 15, qd = lane >> 4;
    const int x = (int)blockIdx.x;               // 0..255
    const int rowbase = ((x & 7) * 8 + ((x >> 3) & 7)) * 128;
    const int colbase = (x >> 6) * 256;

    f32x4 acc[4][4];
#pragma unroll
    for (int i = 0; i < 4; i++)
#pragma unroll
        for (int j = 0; j < 4; j++) acc[i][j] = f32x4{0.f, 0.f, 0.f, 0.f};

    const bool swapped = (g.mode == 1);

    auto stage = [&](int t, int buf) {
#pragma unroll
        for (int c = 0; c < 2; c++) {
            int L = c * 512 + tid;
            int row = L >> 3, s16 = L & 7;
            int sc = s16 ^ (row & 7);
            GLD_LDS16(g.A + (size_t)(rowbase + row) * DK + t * 64 + sc * 8, &As[buf][L * 8]);
        }
#pragma unroll
        for (int c = 0; c < 4; c++) {
            int L = c * 512 + tid;
            int row = L >> 3, s16 = L & 7;
            int sc = s16 ^ (row & 7);
            GLD_LDS16(g.BT + (size_t)(colbase + row) * DK + t * 64 + sc * 8, &Bs[buf][L * 8]);
        }
    };

    stage(0, 0);
    stage(1, 1);

    auto ktile = [&](int t, int cur, bool doStage, bool last) __attribute__((always_inline)) {
        if (last) asm volatile("s_waitcnt vmcnt(0)" ::: "memory");
        else      asm volatile("s_waitcnt vmcnt(6)" ::: "memory");
        asm volatile("s_barrier" ::: "memory");          // tile t visible everywhere
        bf16x8 a0[4], b0[4], a1[4], b1[4];
#pragma unroll
        for (int i = 0; i < 4; i++)
            a0[i] = *(const bf16x8*)&As[cur][(wm + i * 16 + cl) * 64 + ((qd ^ (cl & 7)) * 8)];
#pragma unroll
        for (int j = 0; j < 4; j++)
            b0[j] = *(const bf16x8*)&Bs[cur][(wn + j * 16 + cl) * 64 + ((qd ^ (cl & 7)) * 8)];
#pragma unroll
        for (int i = 0; i < 4; i++)
            a1[i] = *(const bf16x8*)&As[cur][(wm + i * 16 + cl) * 64 + (((4 + qd) ^ (cl & 7)) * 8)];
#pragma unroll
        for (int j = 0; j < 4; j++)
            b1[j] = *(const bf16x8*)&Bs[cur][(wn + j * 16 + cl) * 64 + (((4 + qd) ^ (cl & 7)) * 8)];
        __builtin_amdgcn_s_setprio(1);
        if (swapped) {
#pragma unroll
            for (int i = 0; i < 4; i++)
#pragma unroll
                for (int j = 0; j < 4; j++)
                    acc[i][j] = __builtin_amdgcn_mfma_f32_16x16x32_bf16(b0[j], a0[i], acc[i][j], 0, 0, 0);
        } else {
#pragma unroll
            for (int i = 0; i < 4; i++)
#pragma unroll
                for (int j = 0; j < 4; j++)
                    acc[i][j] = __builtin_amdgcn_mfma_f32_16x16x32_bf16(a0[i], b0[j], acc[i][j], 0, 0, 0);
        }
        __builtin_amdgcn_s_setprio(0);
        asm volatile("s_waitcnt lgkmcnt(0)" ::: "memory");  // ALL reads of buf[cur] retired
        asm volatile("s_barrier" ::: "memory");             // buffer free for restage
        if (doStage) stage(t + 2, cur);                     // in flight during k1 MFMAs
        __builtin_amdgcn_s_setprio(1);
        if (swapped) {
#pragma unroll
            for (int i = 0; i < 4; i++)
#pragma unroll
                for (int j = 0; j < 4; j++)
                    acc[i][j] = __builtin_amdgcn_mfma_f32_16x16x32_bf16(b1[j], a1[i], acc[i][j], 0, 0, 0);
        } else {
#pragma unroll
            for (int i = 0; i < 4; i++)
#pragma unroll
                for (int j = 0; j < 4; j++)
                    acc[i][j] = __builtin_amdgcn_mfma_f32_16x16x32_bf16(a1[i], b1[j], acc[i][j], 0, 0, 0);
        }
        __builtin_amdgcn_s_setprio(0);
    };

    for (int t = 0; t < 14; ++t) ktile(t, t & 1, true, false);
    ktile(14, 0, false, false);
    ktile(15, 1, false, true);

    if (g.mode == 2) {
        float* out = (float*)g.out;
#pragma unroll
        for (int i = 0; i < 4; i++)
#pragma unroll
            for (int j = 0; j < 4; j++)
#pragma unroll
                for (int r = 0; r < 4; r++) {
                    int row = rowbase + wm + i * 16 + qd * 4 + r;
                    int col = colbase + wn + j * 16 + cl;
                    out[(size_t)row * DK + col] = (acc[i][j][r] + g.bias[col]) * g.oscale;
                }
    } else if (g.mode == 0) {
        bf16* out = (bf16*)g.out;
#pragma unroll
        for (int i = 0; i < 4; i++)
#pragma unroll
            for (int j = 0; j < 4; j++)
#pragma unroll
                for (int r = 0; r < 4; r++) {
                    int row = rowbase + wm + i * 16 + qd * 4 + r;
                    int col = colbase + wn + j * 16 + cl;
                    float v = (acc[i][j][r] + g.bias[col]) * g.oscale;
                    out[(size_t)row * DK + col] = (bf16)v;
                }
    } else {
        // transposed epilogue: acc holds C^T tile — rows = cols(h,d), cols = rows(s)
        bf16* out = (bf16*)g.out;   // (B,H,64,S)
#pragma unroll
        for (int i = 0; i < 4; i++)
#pragma unroll
            for (int j = 0; j < 4; j++)
#pragma unroll
                for (int r = 0; r < 4; r++) {
                    int colg = colbase + wn + j * 16 + qd * 4 + r;   // h*64+d
                    int rowg = rowbase + wm + i * 16 + cl;           // b*2048+s
                    int b_ = rowg >> 11, s_ = rowg & 2047;
                    float v = (acc[i][j][r] + g.bias[colg]) * g.oscale;
                    out[((size_t)(b_ * NH + (colg >> 6)) * DH + (colg & 63)) * SSEQ + s_] = (bf16)v;
                }
    }
}

// ---------------------------------------------------------------- flash attention
// grid 1024 blocks (XCD-swizzled). block 256 = 4 waves; wave w owns 32 queries.
// S^T = K·Q^T via 16x16x32 (C-layout: key=qd*4+r, query=cl).
// KEY PERMUTATION: K rows staged permuted by pi so post-exp2 P fragments are
// directly the full-rate PV B-operand (see R2). PV: O^T = V^T·P^T, 16x16x32.
// R8: softmax denominator via ONES-MFMA — La[mi] = mfma(ones, pf8[mi][g], La)
// sums all 32 keys per g on the MATRIX pipe (A=ones is layout-invariant;
// D[*][cl] = l for query cl, identical in every lane/register). Removes the
// 32 serial VALU adds per lane/iter AND the epilogue shfl reduce. R7 counters:
// VALU 50% > MFMA 37% -> shift work to the idler pipe.
__global__ __launch_bounds__(256, 4) void attn(const bf16* __restrict__ Qh,
                                               const bf16* __restrict__ Kh,
                                               const bf16* __restrict__ VTh,
                                               bf16* __restrict__ mrg) {
    __shared__ __attribute__((aligned(16))) bf16 Ks[2][64 * 64];   // [perm key][d], swizzled
    __shared__ __attribute__((aligned(16))) bf16 VTs[2][64 * 64];  // [d][key], swizzled
    const int tid = threadIdx.x;
    const int lane = tid & 63, w = tid >> 6;
    const int cl = lane & 15, qd = lane >> 4;
    // XCD swizzle: 8 bh values per XCD -> K/V working set = 4 MB = one L2
    const int F = blockIdx.x;            // 0..1023
    const int xcd = F & 7, slot = F >> 3;
    const int bh = xcd * 8 + (slot & 7);
    const int qt = slot >> 3;            // 0..15
    const int b_ = bh >> 4, h_ = bh & 15;
    const int qbase = qt * 128;
    const bf16* Qb = Qh + ((size_t)b_ * SSEQ) * DK + h_ * DH;   // row stride DK
    const bf16* Kb = Kh + ((size_t)b_ * SSEQ) * DK + h_ * DH;
    const bf16* Vb = VTh + (size_t)bh * DH * SSEQ;

    // Q fragments (B-operand of S^T): lane n=cl=query, k=d. Pre-scaled by log2(e)/8.
    bf16x8 qf[2][2];
#pragma unroll
    for (int mi = 0; mi < 2; mi++) {
        int q = qbase + w * 32 + mi * 16 + cl;
        qf[mi][0] = *(const bf16x8*)&Qb[(size_t)q * DK + qd * 8];
        qf[mi][1] = *(const bf16x8*)&Qb[(size_t)q * DK + 32 + qd * 8];
    }
    f32x4 O[2][4];   // O^T tiles: [query-tile][d-tile], lane: query=cl, d=qd*4+r
#pragma unroll
    for (int mi = 0; mi < 2; mi++)
#pragma unroll
        for (int jv = 0; jv < 4; jv++) O[mi][jv] = f32x4{0.f, 0.f, 0.f, 0.f};
    f32x4 La[2] = { f32x4{0.f, 0.f, 0.f, 0.f}, f32x4{0.f, 0.f, 0.f, 0.f} };
    bf16x8 ones8;
#pragma unroll
    for (int r = 0; r < 8; r++) ones8[r] = (bf16)1.0f;

    // stage tile kt into buffer buf. K rows permuted by pi; V unpermuted.
    auto stage = [&](int kt, int buf) {
#pragma unroll
        for (int c = 0; c < 2; c++) {
            int L = c * 256 + tid;
            int row = L >> 3, lc = (L & 7) ^ (row & 7);
            int prow = ((row >> 5) << 5) | (((row >> 2) & 3) << 3)
                     | (((row >> 4) & 1) << 2) | (row & 3);      // pi(row)
            GLD_LDS16(Kb + (size_t)(kt * 64 + prow) * DK + lc * 8, &Ks[buf][L * 8]);
        }
#pragma unroll
        for (int c = 0; c < 2; c++) {
            int L = c * 256 + tid;
            int row = L >> 3, lc = (L & 7) ^ (row & 7);
            GLD_LDS16(Vb + (size_t)row * SSEQ + kt * 64 + lc * 8, &VTs[buf][L * 8]);
        }
    };
    stage(0, 0);

    for (int kt = 0; kt < 32; kt++) {
        const int buf = kt & 1;
        __syncthreads();                 // tile kt staged; prev reads of buf^1 done
        if (kt + 1 < 32) stage(kt + 1, buf ^ 1);

        // S^T = K Q^T, exp2 -> P^T register fragments.
        // pf8[mi][g][ (jt&1)*4 + r ] = P[phys 32g+8qd+4*(jt&1)+r][query cl]
        bf16x8 pf8[2][2];
#pragma unroll
        for (int jt = 0; jt < 4; jt++) {
            bf16x8 kf0 = *(const bf16x8*)&Ks[buf][(jt * 16 + cl) * 64 + ((qd ^ (cl & 7)) * 8)];
            bf16x8 kf1 = *(const bf16x8*)&Ks[buf][(jt * 16 + cl) * 64 + (((4 + qd) ^ (cl & 7)) * 8)];
#pragma unroll
            for (int mi = 0; mi < 2; mi++) {
                f32x4 S = __builtin_amdgcn_mfma_f32_16x16x32_bf16(kf0, qf[mi][0],
                                                                  f32x4{0.f, 0.f, 0.f, 0.f}, 0, 0, 0);
                S = __builtin_amdgcn_mfma_f32_16x16x32_bf16(kf1, qf[mi][1], S, 0, 0, 0);
#pragma unroll
                for (int r = 0; r < 4; r++)
                    pf8[mi][jt >> 1][(jt & 1) * 4 + r] = (bf16)__builtin_amdgcn_exp2f(S[r]);
            }
        }

        // O^T += V^T P^T; l += ones·P^T (denominator on the matrix pipe)
#pragma unroll
        for (int g = 0; g < 2; g++) {
#pragma unroll
            for (int jv = 0; jv < 4; jv++) {
                bf16x8 vf = *(const bf16x8*)&VTs[buf][(jv * 16 + cl) * 64 +
                                (((g * 4 + qd) ^ (cl & 7)) * 8)];
#pragma unroll
                for (int mi = 0; mi < 2; mi++)
                    O[mi][jv] = __builtin_amdgcn_mfma_f32_16x16x32_bf16(vf, pf8[mi][g], O[mi][jv], 0, 0, 0);
            }
#pragma unroll
            for (int mi = 0; mi < 2; mi++)
                La[mi] = __builtin_amdgcn_mfma_f32_16x16x32_bf16(ones8, pf8[mi][g], La[mi], 0, 0, 0);
        }
    }

    // epilogue: every lane already holds l(query cl) in La[mi][0] — no shfl.
#pragma unroll
    for (int mi = 0; mi < 2; mi++) {
        float inv = 1.0f / La[mi][0];
        int q = qbase + w * 32 + mi * 16 + cl;
        size_t ro = ((size_t)(b_ * SSEQ + q)) * DK + h_ * DH;
#pragma unroll
        for (int jv = 0; jv < 4; jv++) {
            bf16x4 o4;
#pragma unroll
            for (int r = 0; r < 4; r++) o4[r] = (bf16)(O[mi][jv][r] * inv);
            *(bf16x4*)&mrg[ro + jv * 16 + qd * 4] = o4;
        }
    }
}

// ---------------------------------------------------------------- launch
extern "C" void kernel_launch(void* const* d_in, const int* in_sizes, int n_in,
                              void* d_out, int out_size, void* d_ws, size_t ws_size,
                              hipStream_t stream) {
    const float* q  = (const float*)d_in[0];
    const float* k  = (const float*)d_in[1];
    const float* v  = (const float*)d_in[2];
    const float* Wq = (const float*)d_in[3];
    const float* bq = (const float*)d_in[4];
    const float* Wk = (const float*)d_in[5];
    const float* bk = (const float*)d_in[6];
    const float* Wv = (const float*)d_in[7];
    const float* bv = (const float*)d_in[8];
    const float* Wu = (const float*)d_in[9];
    const float* bu = (const float*)d_in[10];
    char* ws = (char*)d_ws;
    bf16* qbf = (bf16*)(ws + OFF_QBF);
    bf16* kbf = (bf16*)(ws + OFF_KBF);
    bf16* vbf = (bf16*)(ws + OFF_VBF);
    bf16* wqt = (bf16*)(ws + OFF_WQT);
    bf16* wkt = (bf16*)(ws + OFF_WKT);
    bf16* wvt = (bf16*)(ws + OFF_WVT);
    bf16* wut = (bf16*)(ws + OFF_WUT);
    bf16* qh  = (bf16*)(ws + OFF_QH);
    bf16* kh  = (bf16*)(ws + OFF_KH);
    bf16* vth = (bf16*)(ws + OFF_VTH);
    bf16* mrg = (bf16*)(ws + OFF_MRG);

    cvt_x<<<dim3(8192, 1, 3), 256, 0, stream>>>(q, k, v, qbf, kbf, vbf);
    cvt_wT<<<dim3(16, 16, 4), 256, 0, stream>>>(Wq, Wk, Wv, Wu, wqt, wkt, wvt, wut);

    // Q projection folds score scale AND log2(e) for exp2-softmax: 0.125 * log2(e)
    GArg gq{qbf, wqt, bq, (void*)qh, 0, 0.18033688011112043f};
    GArg gk{kbf, wkt, bk, (void*)kh, 0, 1.0f};
    GArg gv{vbf, wvt, bv, (void*)vth, 1, 1.0f};
    gemm_bt<<<dim3(256, 1, 3), 512, 0, stream>>>(gq, gk, gv);

    attn<<<dim3(1024), 256, 0, stream>>>(qh, kh, vth, mrg);

    GArg go{mrg, wut, bu, d_out, 2, 1.0f};
    gemm_bt<<<dim3(256, 1, 1), 512, 0, stream>>>(go, go, go);
}

// Round 9
// 323.521 us; speedup vs baseline: 1.0150x; 1.0150x over previous
//
#include <hip/hip_runtime.h>

typedef __bf16 bf16;
typedef __bf16 bf16x8 __attribute__((ext_vector_type(8)));
typedef __bf16 bf16x4 __attribute__((ext_vector_type(4)));
typedef float  f32x4  __attribute__((ext_vector_type(4)));

#define GLD_LDS16(gp, lp) __builtin_amdgcn_global_load_lds( \
    (const __attribute__((address_space(1))) unsigned int*)(const void*)(gp), \
    (__attribute__((address_space(3))) unsigned int*)(void*)(lp), 16, 0, 0)

constexpr int BB = 4, SSEQ = 2048, DK = 1024, NH = 16, DH = 64;
constexpr int M = BB * SSEQ;                    // 8192 rows

constexpr size_t SZ_X = (size_t)M * DK * 2;     // 16 MiB
constexpr size_t SZ_W = (size_t)DK * DK * 2;    // 2 MiB
constexpr size_t OFF_QBF = 0;
constexpr size_t OFF_KBF = OFF_QBF + SZ_X;
constexpr size_t OFF_VBF = OFF_KBF + SZ_X;
constexpr size_t OFF_WQT = OFF_VBF + SZ_X;
constexpr size_t OFF_WKT = OFF_WQT + SZ_W;
constexpr size_t OFF_WVT = OFF_WKT + SZ_W;
constexpr size_t OFF_WUT = OFF_WVT + SZ_W;
constexpr size_t OFF_QH  = OFF_WUT + SZ_W;      // (B,S,1024) bf16 flat
constexpr size_t OFF_KH  = OFF_QH + SZ_X;       // (B,S,1024) bf16 flat
constexpr size_t OFF_VTH = OFF_KH + SZ_X;       // (B,H,64,S) bf16 (transposed)
constexpr size_t OFF_MRG = OFF_VTH + SZ_X;      // (B,S,1024) bf16

// ---------------------------------------------------------------- converts
__global__ void cvt_x(const float* __restrict__ q, const float* __restrict__ k,
                      const float* __restrict__ v,
                      bf16* __restrict__ qb, bf16* __restrict__ kb, bf16* __restrict__ vb) {
    const float* s = (blockIdx.z == 0) ? q : (blockIdx.z == 1) ? k : v;
    bf16*        d = (blockIdx.z == 0) ? qb : (blockIdx.z == 1) ? kb : vb;
    size_t i = (size_t)blockIdx.x * blockDim.x + threadIdx.x;
    float4 val = ((const float4*)s)[i];
    bf16x4 o = { (bf16)val.x, (bf16)val.y, (bf16)val.z, (bf16)val.w };
    ((bf16x4*)d)[i] = o;
}

__global__ void cvt_wT(const float* __restrict__ wq, const float* __restrict__ wk,
                       const float* __restrict__ wv, const float* __restrict__ wu,
                       bf16* __restrict__ wqt, bf16* __restrict__ wkt,
                       bf16* __restrict__ wvt, bf16* __restrict__ wut) {
    const float* w = (blockIdx.z == 0) ? wq : (blockIdx.z == 1) ? wk
                   : (blockIdx.z == 2) ? wv : wu;
    bf16* o        = (blockIdx.z == 0) ? wqt : (blockIdx.z == 1) ? wkt
                   : (blockIdx.z == 2) ? wvt : wut;
    __shared__ float t[64][65];
    int tx = threadIdx.x & 63, ty = threadIdx.x >> 6;
    int bx = blockIdx.x * 64, by = blockIdx.y * 64;
#pragma unroll
    for (int r = 0; r < 16; r++) {
        int row = ty * 16 + r;
        t[row][tx] = w[(size_t)(by + row) * DK + bx + tx];
    }
    __syncthreads();
#pragma unroll
    for (int r = 0; r < 16; r++) {
        int row2 = ty * 16 + r;
        o[(size_t)(bx + row2) * DK + by + tx] = (bf16)t[tx][row2];
    }
}

// ---------------------------------------------------------------- GEMM (C = A @ BT^T + bias)
// R7 schedule (verified race-free): 8-wave 128xBN x64 tile, raw s_barrier +
// counted vmcnt (T3+T4), T2 XOR-swizzle via pre-swizzled global source, T5
// setprio. Sync: BAR1 after vmcnt(N): tile t landed. BAR2 after lgkmcnt(0):
// all reads of buf[cur] retired -> stage(t+2) may overwrite.
// R9: BN templated. QKV: BN=256 (6 loads/tile, vmcnt(6), grid 256/z = 3 CU
// rounds). Proj: BN=128 (4 loads/tile, vmcnt(4), grid 512 = 2 blocks/CU —
// R7's 256-block proj had 1 block/CU: zero cross-block TLP to cover barriers).
// mode 0: out bf16 row-major; mode 1: out bf16 (B,H,64,S); mode 2: out f32
struct GArg {
    const bf16* A; const bf16* BT; const float* bias; void* out; int mode; float oscale;
};

template<int BNT>
__global__ __launch_bounds__(512, 2) void gemm_bt(GArg g0, GArg g1, GArg g2) {
    GArg g;
    if (blockIdx.z == 0) g = g0; else if (blockIdx.z == 1) g = g1; else g = g2;
    constexpr int JN = BNT / 64;                  // per-wave 16-col tiles (4 or 2)
    __shared__ __attribute__((aligned(16))) bf16 As[2][128 * 64];
    __shared__ __attribute__((aligned(16))) bf16 Bs[2][BNT * 64];
    const int tid = threadIdx.x;                 // 0..511
    const int lane = tid & 63, wv = tid >> 6;    // 8 waves
    const int wm = (wv >> 2) * 64;               // 0,64   (2 row-groups)
    const int wn = (wv & 3) * (BNT / 4);         // 4 col-groups
    const int cl = lane & 15, qd = lane >> 4;
    const int x = (int)blockIdx.x;
    const int rowbase = ((x & 7) * 8 + ((x >> 3) & 7)) * 128;
    const int colbase = (x >> 6) * BNT;

    f32x4 acc[4][JN];
#pragma unroll
    for (int i = 0; i < 4; i++)
#pragma unroll
        for (int j = 0; j < JN; j++) acc[i][j] = f32x4{0.f, 0.f, 0.f, 0.f};

    const bool swapped = (g.mode == 1);

    auto stage = [&](int t, int buf) {
#pragma unroll
        for (int c = 0; c < 2; c++) {
            int L = c * 512 + tid;
            int row = L >> 3, s16 = L & 7;
            int sc = s16 ^ (row & 7);
            GLD_LDS16(g.A + (size_t)(rowbase + row) * DK + t * 64 + sc * 8, &As[buf][L * 8]);
        }
#pragma unroll
        for (int c = 0; c < BNT / 64; c++) {
            int L = c * 512 + tid;
            int row = L >> 3, s16 = L & 7;
            int sc = s16 ^ (row & 7);
            GLD_LDS16(g.BT + (size_t)(colbase + row) * DK + t * 64 + sc * 8, &Bs[buf][L * 8]);
        }
    };

    stage(0, 0);
    stage(1, 1);

    auto ktile = [&](int t, int cur, bool doStage, bool last) __attribute__((always_inline)) {
        if (last) asm volatile("s_waitcnt vmcnt(0)" ::: "memory");
        else if constexpr (BNT == 256) asm volatile("s_waitcnt vmcnt(6)" ::: "memory");
        else                           asm volatile("s_waitcnt vmcnt(4)" ::: "memory");
        asm volatile("s_barrier" ::: "memory");          // tile t visible everywhere
        bf16x8 a0[4], b0[JN], a1[4], b1[JN];
#pragma unroll
        for (int i = 0; i < 4; i++)
            a0[i] = *(const bf16x8*)&As[cur][(wm + i * 16 + cl) * 64 + ((qd ^ (cl & 7)) * 8)];
#pragma unroll
        for (int j = 0; j < JN; j++)
            b0[j] = *(const bf16x8*)&Bs[cur][(wn + j * 16 + cl) * 64 + ((qd ^ (cl & 7)) * 8)];
#pragma unroll
        for (int i = 0; i < 4; i++)
            a1[i] = *(const bf16x8*)&As[cur][(wm + i * 16 + cl) * 64 + (((4 + qd) ^ (cl & 7)) * 8)];
#pragma unroll
        for (int j = 0; j < JN; j++)
            b1[j] = *(const bf16x8*)&Bs[cur][(wn + j * 16 + cl) * 64 + (((4 + qd) ^ (cl & 7)) * 8)];
        __builtin_amdgcn_s_setprio(1);
        if (swapped) {
#pragma unroll
            for (int i = 0; i < 4; i++)
#pragma unroll
                for (int j = 0; j < JN; j++)
                    acc[i][j] = __builtin_amdgcn_mfma_f32_16x16x32_bf16(b0[j], a0[i], acc[i][j], 0, 0, 0);
        } else {
#pragma unroll
            for (int i = 0; i < 4; i++)
#pragma unroll
                for (int j = 0; j < JN; j++)
                    acc[i][j] = __builtin_amdgcn_mfma_f32_16x16x32_bf16(a0[i], b0[j], acc[i][j], 0, 0, 0);
        }
        __builtin_amdgcn_s_setprio(0);
        asm volatile("s_waitcnt lgkmcnt(0)" ::: "memory");  // ALL reads of buf[cur] retired
        asm volatile("s_barrier" ::: "memory");             // buffer free for restage
        if (doStage) stage(t + 2, cur);                     // in flight during k1 MFMAs
        __builtin_amdgcn_s_setprio(1);
        if (swapped) {
#pragma unroll
            for (int i = 0; i < 4; i++)
#pragma unroll
                for (int j = 0; j < JN; j++)
                    acc[i][j] = __builtin_amdgcn_mfma_f32_16x16x32_bf16(b1[j], a1[i], acc[i][j], 0, 0, 0);
        } else {
#pragma unroll
            for (int i = 0; i < 4; i++)
#pragma unroll
                for (int j = 0; j < JN; j++)
                    acc[i][j] = __builtin_amdgcn_mfma_f32_16x16x32_bf16(a1[i], b1[j], acc[i][j], 0, 0, 0);
        }
        __builtin_amdgcn_s_setprio(0);
    };

    for (int t = 0; t < 14; ++t) ktile(t, t & 1, true, false);
    ktile(14, 0, false, false);
    ktile(15, 1, false, true);

    if (g.mode == 2) {
        float* out = (float*)g.out;
#pragma unroll
        for (int i = 0; i < 4; i++)
#pragma unroll
            for (int j = 0; j < JN; j++)
#pragma unroll
                for (int r = 0; r < 4; r++) {
                    int row = rowbase + wm + i * 16 + qd * 4 + r;
                    int col = colbase + wn + j * 16 + cl;
                    out[(size_t)row * DK + col] = (acc[i][j][r] + g.bias[col]) * g.oscale;
                }
    } else if (g.mode == 0) {
        bf16* out = (bf16*)g.out;
#pragma unroll
        for (int i = 0; i < 4; i++)
#pragma unroll
            for (int j = 0; j < JN; j++)
#pragma unroll
                for (int r = 0; r < 4; r++) {
                    int row = rowbase + wm + i * 16 + qd * 4 + r;
                    int col = colbase + wn + j * 16 + cl;
                    float v = (acc[i][j][r] + g.bias[col]) * g.oscale;
                    out[(size_t)row * DK + col] = (bf16)v;
                }
    } else {
        // transposed epilogue: acc holds C^T tile — rows = cols(h,d), cols = rows(s)
        bf16* out = (bf16*)g.out;   // (B,H,64,S)
#pragma unroll
        for (int i = 0; i < 4; i++)
#pragma unroll
            for (int j = 0; j < JN; j++)
#pragma unroll
                for (int r = 0; r < 4; r++) {
                    int colg = colbase + wn + j * 16 + qd * 4 + r;   // h*64+d
                    int rowg = rowbase + wm + i * 16 + cl;           // b*2048+s
                    int b_ = rowg >> 11, s_ = rowg & 2047;
                    float v = (acc[i][j][r] + g.bias[colg]) * g.oscale;
                    out[((size_t)(b_ * NH + (colg >> 6)) * DH + (colg & 63)) * SSEQ + s_] = (bf16)v;
                }
    }
}

// ---------------------------------------------------------------- flash attention
// R7 version (measured 79.2us; R8's ones-MFMA denominator spilled 8 regs over
// the bounds(256,4) cap — WRITE +8MB — and regressed; reverted).
// grid 1024 blocks (XCD-swizzled). block 256 = 4 waves; wave w owns 32 queries.
// S^T = K·Q^T via 16x16x32 (C-layout: key=qd*4+r, query=cl).
// KEY PERMUTATION: K rows staged permuted by pi so post-exp2 P fragments are
// directly the full-rate PV B-operand. PV: O^T = V^T·P^T, 16x16x32.
// Softmax: fixed max, exp2 (log2(e)/8 folded into Q projection); l reduced at epilogue.
__global__ __launch_bounds__(256, 4) void attn(const bf16* __restrict__ Qh,
                                               const bf16* __restrict__ Kh,
                                               const bf16* __restrict__ VTh,
                                               bf16* __restrict__ mrg) {
    __shared__ __attribute__((aligned(16))) bf16 Ks[2][64 * 64];   // [perm key][d], swizzled
    __shared__ __attribute__((aligned(16))) bf16 VTs[2][64 * 64];  // [d][key], swizzled
    const int tid = threadIdx.x;
    const int lane = tid & 63, w = tid >> 6;
    const int cl = lane & 15, qd = lane >> 4;
    // XCD swizzle: 8 bh values per XCD -> K/V working set = 4 MB = one L2
    const int F = blockIdx.x;            // 0..1023
    const int xcd = F & 7, slot = F >> 3;
    const int bh = xcd * 8 + (slot & 7);
    const int qt = slot >> 3;            // 0..15
    const int b_ = bh >> 4, h_ = bh & 15;
    const int qbase = qt * 128;
    const bf16* Qb = Qh + ((size_t)b_ * SSEQ) * DK + h_ * DH;   // row stride DK
    const bf16* Kb = Kh + ((size_t)b_ * SSEQ) * DK + h_ * DH;
    const bf16* Vb = VTh + (size_t)bh * DH * SSEQ;

    // Q fragments (B-operand of S^T): lane n=cl=query, k=d. Pre-scaled by log2(e)/8.
    bf16x8 qf[2][2];
#pragma unroll
    for (int mi = 0; mi < 2; mi++) {
        int q = qbase + w * 32 + mi * 16 + cl;
        qf[mi][0] = *(const bf16x8*)&Qb[(size_t)q * DK + qd * 8];
        qf[mi][1] = *(const bf16x8*)&Qb[(size_t)q * DK + 32 + qd * 8];
    }
    f32x4 O[2][4];   // O^T tiles: [query-tile][d-tile], lane: query=cl, d=qd*4+r
#pragma unroll
    for (int mi = 0; mi < 2; mi++)
#pragma unroll
        for (int jv = 0; jv < 4; jv++) O[mi][jv] = f32x4{0.f, 0.f, 0.f, 0.f};
    float ps[2] = {0.f, 0.f};

    // stage tile kt into buffer buf. K rows permuted by pi; V unpermuted.
    auto stage = [&](int kt, int buf) {
#pragma unroll
        for (int c = 0; c < 2; c++) {
            int L = c * 256 + tid;
            int row = L >> 3, lc = (L & 7) ^ (row & 7);
            int prow = ((row >> 5) << 5) | (((row >> 2) & 3) << 3)
                     | (((row >> 4) & 1) << 2) | (row & 3);      // pi(row)
            GLD_LDS16(Kb + (size_t)(kt * 64 + prow) * DK + lc * 8, &Ks[buf][L * 8]);
        }
#pragma unroll
        for (int c = 0; c < 2; c++) {
            int L = c * 256 + tid;
            int row = L >> 3, lc = (L & 7) ^ (row & 7);
            GLD_LDS16(Vb + (size_t)row * SSEQ + kt * 64 + lc * 8, &VTs[buf][L * 8]);
        }
    };
    stage(0, 0);

    for (int kt = 0; kt < 32; kt++) {
        const int buf = kt & 1;
        __syncthreads();                 // tile kt staged; prev reads of buf^1 done
        if (kt + 1 < 32) stage(kt + 1, buf ^ 1);

        // S^T = K Q^T, exp2 -> P^T register fragments.
        // pf8[mi][g][ (jt&1)*4 + r ] = P[phys 32g+8qd+4*(jt&1)+r][query cl]
        bf16x8 pf8[2][2];
#pragma unroll
        for (int jt = 0; jt < 4; jt++) {
            bf16x8 kf0 = *(const bf16x8*)&Ks[buf][(jt * 16 + cl) * 64 + ((qd ^ (cl & 7)) * 8)];
            bf16x8 kf1 = *(const bf16x8*)&Ks[buf][(jt * 16 + cl) * 64 + (((4 + qd) ^ (cl & 7)) * 8)];
#pragma unroll
            for (int mi = 0; mi < 2; mi++) {
                f32x4 S = __builtin_amdgcn_mfma_f32_16x16x32_bf16(kf0, qf[mi][0],
                                                                  f32x4{0.f, 0.f, 0.f, 0.f}, 0, 0, 0);
                S = __builtin_amdgcn_mfma_f32_16x16x32_bf16(kf1, qf[mi][1], S, 0, 0, 0);
                float s = 0.f;
#pragma unroll
                for (int r = 0; r < 4; r++) {
                    float p = __builtin_amdgcn_exp2f(S[r]);
                    s += p;
                    pf8[mi][jt >> 1][(jt & 1) * 4 + r] = (bf16)p;
                }
                ps[mi] += s;
            }
        }

        // O^T += V^T P^T  (full-rate 16x16x32; A: V^T bf16x8 from LDS, B: pf8 regs)
#pragma unroll
        for (int g = 0; g < 2; g++) {
#pragma unroll
            for (int jv = 0; jv < 4; jv++) {
                bf16x8 vf = *(const bf16x8*)&VTs[buf][(jv * 16 + cl) * 64 +
                                (((g * 4 + qd) ^ (cl & 7)) * 8)];
#pragma unroll
                for (int mi = 0; mi < 2; mi++)
                    O[mi][jv] = __builtin_amdgcn_mfma_f32_16x16x32_bf16(vf, pf8[mi][g], O[mi][jv], 0, 0, 0);
            }
        }
    }

    // epilogue: reduce l over qd groups, normalize, store merged (B,S,1024)
#pragma unroll
    for (int mi = 0; mi < 2; mi++) {
        float t = ps[mi];
        t += __shfl_xor(t, 16);
        t += __shfl_xor(t, 32);
        float inv = 1.0f / t;
        int q = qbase + w * 32 + mi * 16 + cl;
        size_t ro = ((size_t)(b_ * SSEQ + q)) * DK + h_ * DH;
#pragma unroll
        for (int jv = 0; jv < 4; jv++) {
            bf16x4 o4;
#pragma unroll
            for (int r = 0; r < 4; r++) o4[r] = (bf16)(O[mi][jv][r] * inv);
            *(bf16x4*)&mrg[ro + jv * 16 + qd * 4] = o4;
        }
    }
}

// ---------------------------------------------------------------- launch
extern "C" void kernel_launch(void* const* d_in, const int* in_sizes, int n_in,
                              void* d_out, int out_size, void* d_ws, size_t ws_size,
                              hipStream_t stream) {
    const float* q  = (const float*)d_in[0];
    const float* k  = (const float*)d_in[1];
    const float* v  = (const float*)d_in[2];
    const float* Wq = (const float*)d_in[3];
    const float* bq = (const float*)d_in[4];
    const float* Wk = (const float*)d_in[5];
    const float* bk = (const float*)d_in[6];
    const float* Wv = (const float*)d_in[7];
    const float* bv = (const float*)d_in[8];
    const float* Wu = (const float*)d_in[9];
    const float* bu = (const float*)d_in[10];
    char* ws = (char*)d_ws;
    bf16* qbf = (bf16*)(ws + OFF_QBF);
    bf16* kbf = (bf16*)(ws + OFF_KBF);
    bf16* vbf = (bf16*)(ws + OFF_VBF);
    bf16* wqt = (bf16*)(ws + OFF_WQT);
    bf16* wkt = (bf16*)(ws + OFF_WKT);
    bf16* wvt = (bf16*)(ws + OFF_WVT);
    bf16* wut = (bf16*)(ws + OFF_WUT);
    bf16* qh  = (bf16*)(ws + OFF_QH);
    bf16* kh  = (bf16*)(ws + OFF_KH);
    bf16* vth = (bf16*)(ws + OFF_VTH);
    bf16* mrg = (bf16*)(ws + OFF_MRG);

    cvt_x<<<dim3(8192, 1, 3), 256, 0, stream>>>(q, k, v, qbf, kbf, vbf);
    cvt_wT<<<dim3(16, 16, 4), 256, 0, stream>>>(Wq, Wk, Wv, Wu, wqt, wkt, wvt, wut);

    // Q projection folds score scale AND log2(e) for exp2-softmax: 0.125 * log2(e)
    GArg gq{qbf, wqt, bq, (void*)qh, 0, 0.18033688011112043f};
    GArg gk{kbf, wkt, bk, (void*)kh, 0, 1.0f};
    GArg gv{vbf, wvt, bv, (void*)vth, 1, 1.0f};
    gemm_bt<256><<<dim3(256, 1, 3), 512, 0, stream>>>(gq, gk, gv);

    attn<<<dim3(1024), 256, 0, stream>>>(qh, kh, vth, mrg);

    GArg go{mrg, wut, bu, d_out, 2, 1.0f};
    gemm_bt<128><<<dim3(512, 1, 1), 512, 0, stream>>>(go, go, go);
}

// Round 10
// 319.491 us; speedup vs baseline: 1.0278x; 1.0126x over previous
//
#include <hip/hip_runtime.h>

typedef __bf16 bf16;
typedef __bf16 bf16x8 __attribute__((ext_vector_type(8)));
typedef __bf16 bf16x4 __attribute__((ext_vector_type(4)));
typedef float  f32x4  __attribute__((ext_vector_type(4)));

#define GLD_LDS16(gp, lp) __builtin_amdgcn_global_load_lds( \
    (const __attribute__((address_space(1))) unsigned int*)(const void*)(gp), \
    (__attribute__((address_space(3))) unsigned int*)(void*)(lp), 16, 0, 0)

constexpr int BB = 4, SSEQ = 2048, DK = 1024, NH = 16, DH = 64;
constexpr int M = BB * SSEQ;                    // 8192 rows

constexpr size_t SZ_X = (size_t)M * DK * 2;     // 16 MiB
constexpr size_t SZ_W = (size_t)DK * DK * 2;    // 2 MiB
constexpr size_t OFF_QBF = 0;
constexpr size_t OFF_KBF = OFF_QBF + SZ_X;
constexpr size_t OFF_VBF = OFF_KBF + SZ_X;
constexpr size_t OFF_WQT = OFF_VBF + SZ_X;
constexpr size_t OFF_WKT = OFF_WQT + SZ_W;
constexpr size_t OFF_WVT = OFF_WKT + SZ_W;
constexpr size_t OFF_WUT = OFF_WVT + SZ_W;
constexpr size_t OFF_QH  = OFF_WUT + SZ_W;      // (B,S,1024) bf16 flat
constexpr size_t OFF_KH  = OFF_QH + SZ_X;       // (B,S,1024) bf16 flat
constexpr size_t OFF_VTH = OFF_KH + SZ_X;       // (B,H,64,S) bf16 (transposed)
constexpr size_t OFF_MRG = OFF_VTH + SZ_X;      // (B,S,1024) bf16

// ---------------------------------------------------------------- converts
__global__ void cvt_x(const float* __restrict__ q, const float* __restrict__ k,
                      const float* __restrict__ v,
                      bf16* __restrict__ qb, bf16* __restrict__ kb, bf16* __restrict__ vb) {
    const float* s = (blockIdx.z == 0) ? q : (blockIdx.z == 1) ? k : v;
    bf16*        d = (blockIdx.z == 0) ? qb : (blockIdx.z == 1) ? kb : vb;
    size_t i = (size_t)blockIdx.x * blockDim.x + threadIdx.x;
    float4 val = ((const float4*)s)[i];
    bf16x4 o = { (bf16)val.x, (bf16)val.y, (bf16)val.z, (bf16)val.w };
    ((bf16x4*)d)[i] = o;
}

__global__ void cvt_wT(const float* __restrict__ wq, const float* __restrict__ wk,
                       const float* __restrict__ wv, const float* __restrict__ wu,
                       bf16* __restrict__ wqt, bf16* __restrict__ wkt,
                       bf16* __restrict__ wvt, bf16* __restrict__ wut) {
    const float* w = (blockIdx.z == 0) ? wq : (blockIdx.z == 1) ? wk
                   : (blockIdx.z == 2) ? wv : wu;
    bf16* o        = (blockIdx.z == 0) ? wqt : (blockIdx.z == 1) ? wkt
                   : (blockIdx.z == 2) ? wvt : wut;
    __shared__ float t[64][65];
    int tx = threadIdx.x & 63, ty = threadIdx.x >> 6;
    int bx = blockIdx.x * 64, by = blockIdx.y * 64;
#pragma unroll
    for (int r = 0; r < 16; r++) {
        int row = ty * 16 + r;
        t[row][tx] = w[(size_t)(by + row) * DK + bx + tx];
    }
    __syncthreads();
#pragma unroll
    for (int r = 0; r < 16; r++) {
        int row2 = ty * 16 + r;
        o[(size_t)(bx + row2) * DK + by + tx] = (bf16)t[tx][row2];
    }
}

// ---------------------------------------------------------------- GEMM (C = A @ BT^T + bias)
// R7 schedule (verified race-free): 8-wave 128xBN x64 tile, raw s_barrier +
// counted vmcnt (T3+T4), T2 XOR-swizzle via pre-swizzled global source, T5
// setprio. Sync: BAR1 after vmcnt(N): tile t landed. BAR2 after lgkmcnt(0):
// all reads of buf[cur] retired -> stage(t+2) may overwrite.
// QKV: BN=256 (vmcnt(6), grid 256/z = 3 CU rounds). Proj: BN=128 (vmcnt(4),
// grid 512 = 2 blocks/CU; R9: ~neutral vs BN=256, kept for residency).
// mode 0: out bf16 row-major; mode 1: out bf16 (B,H,64,S); mode 2: out f32
struct GArg {
    const bf16* A; const bf16* BT; const float* bias; void* out; int mode; float oscale;
};

template<int BNT>
__global__ __launch_bounds__(512, 2) void gemm_bt(GArg g0, GArg g1, GArg g2) {
    GArg g;
    if (blockIdx.z == 0) g = g0; else if (blockIdx.z == 1) g = g1; else g = g2;
    constexpr int JN = BNT / 64;                  // per-wave 16-col tiles (4 or 2)
    __shared__ __attribute__((aligned(16))) bf16 As[2][128 * 64];
    __shared__ __attribute__((aligned(16))) bf16 Bs[2][BNT * 64];
    const int tid = threadIdx.x;                 // 0..511
    const int lane = tid & 63, wv = tid >> 6;    // 8 waves
    const int wm = (wv >> 2) * 64;               // 0,64   (2 row-groups)
    const int wn = (wv & 3) * (BNT / 4);         // 4 col-groups
    const int cl = lane & 15, qd = lane >> 4;
    const int x = (int)blockIdx.x;
    const int rowbase = ((x & 7) * 8 + ((x >> 3) & 7)) * 128;
    const int colbase = (x >> 6) * BNT;

    f32x4 acc[4][JN];
#pragma unroll
    for (int i = 0; i < 4; i++)
#pragma unroll
        for (int j = 0; j < JN; j++) acc[i][j] = f32x4{0.f, 0.f, 0.f, 0.f};

    const bool swapped = (g.mode == 1);

    auto stage = [&](int t, int buf) {
#pragma unroll
        for (int c = 0; c < 2; c++) {
            int L = c * 512 + tid;
            int row = L >> 3, s16 = L & 7;
            int sc = s16 ^ (row & 7);
            GLD_LDS16(g.A + (size_t)(rowbase + row) * DK + t * 64 + sc * 8, &As[buf][L * 8]);
        }
#pragma unroll
        for (int c = 0; c < BNT / 64; c++) {
            int L = c * 512 + tid;
            int row = L >> 3, s16 = L & 7;
            int sc = s16 ^ (row & 7);
            GLD_LDS16(g.BT + (size_t)(colbase + row) * DK + t * 64 + sc * 8, &Bs[buf][L * 8]);
        }
    };

    stage(0, 0);
    stage(1, 1);

    auto ktile = [&](int t, int cur, bool doStage, bool last) __attribute__((always_inline)) {
        if (last) asm volatile("s_waitcnt vmcnt(0)" ::: "memory");
        else if constexpr (BNT == 256) asm volatile("s_waitcnt vmcnt(6)" ::: "memory");
        else                           asm volatile("s_waitcnt vmcnt(4)" ::: "memory");
        asm volatile("s_barrier" ::: "memory");          // tile t visible everywhere
        bf16x8 a0[4], b0[JN], a1[4], b1[JN];
#pragma unroll
        for (int i = 0; i < 4; i++)
            a0[i] = *(const bf16x8*)&As[cur][(wm + i * 16 + cl) * 64 + ((qd ^ (cl & 7)) * 8)];
#pragma unroll
        for (int j = 0; j < JN; j++)
            b0[j] = *(const bf16x8*)&Bs[cur][(wn + j * 16 + cl) * 64 + ((qd ^ (cl & 7)) * 8)];
#pragma unroll
        for (int i = 0; i < 4; i++)
            a1[i] = *(const bf16x8*)&As[cur][(wm + i * 16 + cl) * 64 + (((4 + qd) ^ (cl & 7)) * 8)];
#pragma unroll
        for (int j = 0; j < JN; j++)
            b1[j] = *(const bf16x8*)&Bs[cur][(wn + j * 16 + cl) * 64 + (((4 + qd) ^ (cl & 7)) * 8)];
        __builtin_amdgcn_s_setprio(1);
        if (swapped) {
#pragma unroll
            for (int i = 0; i < 4; i++)
#pragma unroll
                for (int j = 0; j < JN; j++)
                    acc[i][j] = __builtin_amdgcn_mfma_f32_16x16x32_bf16(b0[j], a0[i], acc[i][j], 0, 0, 0);
        } else {
#pragma unroll
            for (int i = 0; i < 4; i++)
#pragma unroll
                for (int j = 0; j < JN; j++)
                    acc[i][j] = __builtin_amdgcn_mfma_f32_16x16x32_bf16(a0[i], b0[j], acc[i][j], 0, 0, 0);
        }
        __builtin_amdgcn_s_setprio(0);
        asm volatile("s_waitcnt lgkmcnt(0)" ::: "memory");  // ALL reads of buf[cur] retired
        asm volatile("s_barrier" ::: "memory");             // buffer free for restage
        if (doStage) stage(t + 2, cur);                     // in flight during k1 MFMAs
        __builtin_amdgcn_s_setprio(1);
        if (swapped) {
#pragma unroll
            for (int i = 0; i < 4; i++)
#pragma unroll
                for (int j = 0; j < JN; j++)
                    acc[i][j] = __builtin_amdgcn_mfma_f32_16x16x32_bf16(b1[j], a1[i], acc[i][j], 0, 0, 0);
        } else {
#pragma unroll
            for (int i = 0; i < 4; i++)
#pragma unroll
                for (int j = 0; j < JN; j++)
                    acc[i][j] = __builtin_amdgcn_mfma_f32_16x16x32_bf16(a1[i], b1[j], acc[i][j], 0, 0, 0);
        }
        __builtin_amdgcn_s_setprio(0);
    };

    for (int t = 0; t < 14; ++t) ktile(t, t & 1, true, false);
    ktile(14, 0, false, false);
    ktile(15, 1, false, true);

    if (g.mode == 2) {
        float* out = (float*)g.out;
#pragma unroll
        for (int i = 0; i < 4; i++)
#pragma unroll
            for (int j = 0; j < JN; j++)
#pragma unroll
                for (int r = 0; r < 4; r++) {
                    int row = rowbase + wm + i * 16 + qd * 4 + r;
                    int col = colbase + wn + j * 16 + cl;
                    out[(size_t)row * DK + col] = (acc[i][j][r] + g.bias[col]) * g.oscale;
                }
    } else if (g.mode == 0) {
        bf16* out = (bf16*)g.out;
#pragma unroll
        for (int i = 0; i < 4; i++)
#pragma unroll
            for (int j = 0; j < JN; j++)
#pragma unroll
                for (int r = 0; r < 4; r++) {
                    int row = rowbase + wm + i * 16 + qd * 4 + r;
                    int col = colbase + wn + j * 16 + cl;
                    float v = (acc[i][j][r] + g.bias[col]) * g.oscale;
                    out[(size_t)row * DK + col] = (bf16)v;
                }
    } else {
        // transposed epilogue: acc holds C^T tile — rows = cols(h,d), cols = rows(s)
        bf16* out = (bf16*)g.out;   // (B,H,64,S)
#pragma unroll
        for (int i = 0; i < 4; i++)
#pragma unroll
            for (int j = 0; j < JN; j++)
#pragma unroll
                for (int r = 0; r < 4; r++) {
                    int colg = colbase + wn + j * 16 + qd * 4 + r;   // h*64+d
                    int rowg = rowbase + wm + i * 16 + cl;           // b*2048+s
                    int b_ = rowg >> 11, s_ = rowg & 2047;
                    float v = (acc[i][j][r] + g.bias[colg]) * g.oscale;
                    out[((size_t)(b_ * NH + (colg >> 6)) * DH + (colg & 63)) * SSEQ + s_] = (bf16)v;
                }
    }
}

// ---------------------------------------------------------------- flash attention
// grid 1024 blocks (XCD-swizzled). block 256 = 4 waves; wave w owns 32 queries.
// S^T = K·Q^T via 16x16x32 (C-layout: key=qd*4+r, query=cl).
// KEY PERMUTATION: K rows staged permuted by pi so post-exp2 P fragments are
// directly the full-rate PV B-operand. PV: O^T = V^T·P^T, 16x16x32.
// R10: ones-MFMA denominator RE-LANDED (R8's mechanism was verified: VALU
// 50->37.6%, correctness OK; regression was an 8-reg spill under the
// bounds(256,4)=128-reg cap: WRITE +8.4MB). Fix: bounds(256,3) (cap 170 >=
// ~110 total regs). Effective occupancy was ~2.7 blocks/CU anyway (33.6%).
// Plus T5 setprio around MFMA clusters (guide m191: +4-7% attn).
__global__ __launch_bounds__(256, 3) void attn(const bf16* __restrict__ Qh,
                                               const bf16* __restrict__ Kh,
                                               const bf16* __restrict__ VTh,
                                               bf16* __restrict__ mrg) {
    __shared__ __attribute__((aligned(16))) bf16 Ks[2][64 * 64];   // [perm key][d], swizzled
    __shared__ __attribute__((aligned(16))) bf16 VTs[2][64 * 64];  // [d][key], swizzled
    const int tid = threadIdx.x;
    const int lane = tid & 63, w = tid >> 6;
    const int cl = lane & 15, qd = lane >> 4;
    // XCD swizzle: 8 bh values per XCD -> K/V working set = 4 MB = one L2
    const int F = blockIdx.x;            // 0..1023
    const int xcd = F & 7, slot = F >> 3;
    const int bh = xcd * 8 + (slot & 7);
    const int qt = slot >> 3;            // 0..15
    const int b_ = bh >> 4, h_ = bh & 15;
    const int qbase = qt * 128;
    const bf16* Qb = Qh + ((size_t)b_ * SSEQ) * DK + h_ * DH;   // row stride DK
    const bf16* Kb = Kh + ((size_t)b_ * SSEQ) * DK + h_ * DH;
    const bf16* Vb = VTh + (size_t)bh * DH * SSEQ;

    // Q fragments (B-operand of S^T): lane n=cl=query, k=d. Pre-scaled by log2(e)/8.
    bf16x8 qf[2][2];
#pragma unroll
    for (int mi = 0; mi < 2; mi++) {
        int q = qbase + w * 32 + mi * 16 + cl;
        qf[mi][0] = *(const bf16x8*)&Qb[(size_t)q * DK + qd * 8];
        qf[mi][1] = *(const bf16x8*)&Qb[(size_t)q * DK + 32 + qd * 8];
    }
    f32x4 O[2][4];   // O^T tiles: [query-tile][d-tile], lane: query=cl, d=qd*4+r
#pragma unroll
    for (int mi = 0; mi < 2; mi++)
#pragma unroll
        for (int jv = 0; jv < 4; jv++) O[mi][jv] = f32x4{0.f, 0.f, 0.f, 0.f};
    f32x4 La[2] = { f32x4{0.f, 0.f, 0.f, 0.f}, f32x4{0.f, 0.f, 0.f, 0.f} };
    bf16x8 ones8;
#pragma unroll
    for (int r = 0; r < 8; r++) ones8[r] = (bf16)1.0f;

    // stage tile kt into buffer buf. K rows permuted by pi; V unpermuted.
    auto stage = [&](int kt, int buf) {
#pragma unroll
        for (int c = 0; c < 2; c++) {
            int L = c * 256 + tid;
            int row = L >> 3, lc = (L & 7) ^ (row & 7);
            int prow = ((row >> 5) << 5) | (((row >> 2) & 3) << 3)
                     | (((row >> 4) & 1) << 2) | (row & 3);      // pi(row)
            GLD_LDS16(Kb + (size_t)(kt * 64 + prow) * DK + lc * 8, &Ks[buf][L * 8]);
        }
#pragma unroll
        for (int c = 0; c < 2; c++) {
            int L = c * 256 + tid;
            int row = L >> 3, lc = (L & 7) ^ (row & 7);
            GLD_LDS16(Vb + (size_t)row * SSEQ + kt * 64 + lc * 8, &VTs[buf][L * 8]);
        }
    };
    stage(0, 0);

    for (int kt = 0; kt < 32; kt++) {
        const int buf = kt & 1;
        __syncthreads();                 // tile kt staged; prev reads of buf^1 done
        if (kt + 1 < 32) stage(kt + 1, buf ^ 1);

        // S^T = K Q^T, exp2 -> P^T register fragments.
        // pf8[mi][g][ (jt&1)*4 + r ] = P[phys 32g+8qd+4*(jt&1)+r][query cl]
        bf16x8 pf8[2][2];
#pragma unroll
        for (int jt = 0; jt < 4; jt++) {
            bf16x8 kf0 = *(const bf16x8*)&Ks[buf][(jt * 16 + cl) * 64 + ((qd ^ (cl & 7)) * 8)];
            bf16x8 kf1 = *(const bf16x8*)&Ks[buf][(jt * 16 + cl) * 64 + (((4 + qd) ^ (cl & 7)) * 8)];
#pragma unroll
            for (int mi = 0; mi < 2; mi++) {
                __builtin_amdgcn_s_setprio(1);
                f32x4 S = __builtin_amdgcn_mfma_f32_16x16x32_bf16(kf0, qf[mi][0],
                                                                  f32x4{0.f, 0.f, 0.f, 0.f}, 0, 0, 0);
                S = __builtin_amdgcn_mfma_f32_16x16x32_bf16(kf1, qf[mi][1], S, 0, 0, 0);
                __builtin_amdgcn_s_setprio(0);
#pragma unroll
                for (int r = 0; r < 4; r++)
                    pf8[mi][jt >> 1][(jt & 1) * 4 + r] = (bf16)__builtin_amdgcn_exp2f(S[r]);
            }
        }

        // O^T += V^T P^T; l += ones·P^T (denominator on the matrix pipe)
        __builtin_amdgcn_s_setprio(1);
#pragma unroll
        for (int g = 0; g < 2; g++) {
#pragma unroll
            for (int jv = 0; jv < 4; jv++) {
                bf16x8 vf = *(const bf16x8*)&VTs[buf][(jv * 16 + cl) * 64 +
                                (((g * 4 + qd) ^ (cl & 7)) * 8)];
#pragma unroll
                for (int mi = 0; mi < 2; mi++)
                    O[mi][jv] = __builtin_amdgcn_mfma_f32_16x16x32_bf16(vf, pf8[mi][g], O[mi][jv], 0, 0, 0);
            }
#pragma unroll
            for (int mi = 0; mi < 2; mi++)
                La[mi] = __builtin_amdgcn_mfma_f32_16x16x32_bf16(ones8, pf8[mi][g], La[mi], 0, 0, 0);
        }
        __builtin_amdgcn_s_setprio(0);
    }

    // epilogue: every lane already holds l(query cl) in La[mi][0] — no shfl.
#pragma unroll
    for (int mi = 0; mi < 2; mi++) {
        float inv = 1.0f / La[mi][0];
        int q = qbase + w * 32 + mi * 16 + cl;
        size_t ro = ((size_t)(b_ * SSEQ + q)) * DK + h_ * DH;
#pragma unroll
        for (int jv = 0; jv < 4; jv++) {
            bf16x4 o4;
#pragma unroll
            for (int r = 0; r < 4; r++) o4[r] = (bf16)(O[mi][jv][r] * inv);
            *(bf16x4*)&mrg[ro + jv * 16 + qd * 4] = o4;
        }
    }
}

// ---------------------------------------------------------------- launch
extern "C" void kernel_launch(void* const* d_in, const int* in_sizes, int n_in,
                              void* d_out, int out_size, void* d_ws, size_t ws_size,
                              hipStream_t stream) {
    const float* q  = (const float*)d_in[0];
    const float* k  = (const float*)d_in[1];
    const float* v  = (const float*)d_in[2];
    const float* Wq = (const float*)d_in[3];
    const float* bq = (const float*)d_in[4];
    const float* Wk = (const float*)d_in[5];
    const float* bk = (const float*)d_in[6];
    const float* Wv = (const float*)d_in[7];
    const float* bv = (const float*)d_in[8];
    const float* Wu = (const float*)d_in[9];
    const float* bu = (const float*)d_in[10];
    char* ws = (char*)d_ws;
    bf16* qbf = (bf16*)(ws + OFF_QBF);
    bf16* kbf = (bf16*)(ws + OFF_KBF);
    bf16* vbf = (bf16*)(ws + OFF_VBF);
    bf16* wqt = (bf16*)(ws + OFF_WQT);
    bf16* wkt = (bf16*)(ws + OFF_WKT);
    bf16* wvt = (bf16*)(ws + OFF_WVT);
    bf16* wut = (bf16*)(ws + OFF_WUT);
    bf16* qh  = (bf16*)(ws + OFF_QH);
    bf16* kh  = (bf16*)(ws + OFF_KH);
    bf16* vth = (bf16*)(ws + OFF_VTH);
    bf16* mrg = (bf16*)(ws + OFF_MRG);

    cvt_x<<<dim3(8192, 1, 3), 256, 0, stream>>>(q, k, v, qbf, kbf, vbf);
    cvt_wT<<<dim3(16, 16, 4), 256, 0, stream>>>(Wq, Wk, Wv, Wu, wqt, wkt, wvt, wut);

    // Q projection folds score scale AND log2(e) for exp2-softmax: 0.125 * log2(e)
    GArg gq{qbf, wqt, bq, (void*)qh, 0, 0.18033688011112043f};
    GArg gk{kbf, wkt, bk, (void*)kh, 0, 1.0f};
    GArg gv{vbf, wvt, bv, (void*)vth, 1, 1.0f};
    gemm_bt<256><<<dim3(256, 1, 3), 512, 0, stream>>>(gq, gk, gv);

    attn<<<dim3(1024), 256, 0, stream>>>(qh, kh, vth, mrg);

    GArg go{mrg, wut, bu, d_out, 2, 1.0f};
    gemm_bt<128><<<dim3(512, 1, 1), 512, 0, stream>>>(go, go, go);
}